// Round 20
// baseline (50.333 us; speedup 1.0000x reference)
//
#include <hip/hip_runtime.h>
#include <hip/hip_bf16.h>
#include <math.h>

#define N_CELLS 65536
#define NH 7
#define NV 4
#define E_IN 16
#define E_OUT 16
#define NK 16            // N_OFF * N_SIG

#define CPB 16           // cells per block (2 waves x 2 cell-quads x 4 cells)
#define THREADS 128
#define NWAVES 2
#define TRP 20           // transpose row pad

typedef __attribute__((ext_vector_type(8))) short bf16x8;
typedef __attribute__((ext_vector_type(4))) float f32x4;
typedef __attribute__((ext_vector_type(2))) float f32x2;
typedef unsigned long long u64;

// swizzled nd index (16 cells): row (k, cl) at word (k<<7) + ((cl ^ (k&3))<<3)
#define NDOFF(k, cl) (((k) << 7) + ((((cl) ^ ((k) & 3))) << 3))

// s_waitcnt imm: vmcnt=63 (no wait), expcnt=7 (no wait), lgkmcnt=0 (drain LDS)
#define WAIT_LGKM0 0xC07F

static __device__ __forceinline__ short f2bfs(float f) {
    __hip_bfloat16 h = __float2bfloat16(f);
    short s;
    __builtin_memcpy(&s, &h, 2);
    return s;
}

// ---------------- setup ----------------
// xq[cell][b][v][e] u8 : one cell = one 128B line (both batches)
// meta[cell][8] f32    : {sinlat, coslat, sinlon, coslon, s_b0, s_b1, 0, 0}
// wf : per-lane MFMA B-fragment layout [st][grp][col][j] bf16 (8 KB)
__global__ __launch_bounds__(256) void setup_kernel(
    const float* __restrict__ x, const float* __restrict__ coords,
    const float* __restrict__ W,
    short* __restrict__ wf, unsigned char* __restrict__ xq, float* __restrict__ meta)
{
    const int t = threadIdx.x;
    const int g = blockIdx.x * 64 + (t >> 2);   // group = b*N_CELLS + cell
    const int p = t & 3;

    const float4* src = (const float4*)(x + (size_t)g * 64 + p * 16);
    float4 q[4];
    #pragma unroll
    for (int i = 0; i < 4; ++i) q[i] = src[i];

    float amax = 0.0f;
    #pragma unroll
    for (int i = 0; i < 4; ++i)
        amax = fmaxf(amax, fmaxf(fmaxf(fabsf(q[i].x), fabsf(q[i].y)),
                                 fmaxf(fabsf(q[i].z), fabsf(q[i].w))));
    amax = fmaxf(amax, __shfl_xor(amax, 1));
    amax = fmaxf(amax, __shfl_xor(amax, 2));
    amax = fmaxf(amax, 1e-12f);

    const float inv = 127.0f / amax;
    const float s   = amax / 127.0f;

    unsigned int w[4];
    #pragma unroll
    for (int i = 0; i < 4; ++i) {
        const float vs[4] = {q[i].x, q[i].y, q[i].z, q[i].w};
        unsigned int ww = 0;
        #pragma unroll
        for (int j = 0; j < 4; ++j) {
            float r = rintf(vs[j] * inv);
            r = fminf(fmaxf(r, -127.0f), 127.0f);
            ww |= ((unsigned int)(int)(r + 128.0f) & 0xffu) << (8 * j);
        }
        w[i] = ww;
    }
    const int cell = g & (N_CELLS - 1);
    const int b    = g >> 16;
    *(uint4*)(xq + (size_t)cell * 128 + b * 64 + p * 16) = make_uint4(w[0], w[1], w[2], w[3]);

    if (p == 0) meta[(size_t)cell * 8 + 4 + b] = s;

    if (p == 0 && b == 0) {            // one thread per cell: geometry
        const float lat = coords[cell];
        const float lon = coords[N_CELLS + cell];
        meta[(size_t)cell * 8 + 0] = sinf(lat);
        meta[(size_t)cell * 8 + 1] = cosf(lat);
        meta[(size_t)cell * 8 + 2] = sinf(lon);
        meta[(size_t)cell * 8 + 3] = cosf(lon);
        meta[(size_t)cell * 8 + 6] = 0.0f;
        meta[(size_t)cell * 8 + 7] = 0.0f;
    }

    if (blockIdx.x == 0) {
        const int kk  = t;                 // flat K = k_os*16 + e, 0..255
        const int j   = kk & 7;
        const int grp = (kk >> 3) & 3;
        const int st  = kk >> 5;
        #pragma unroll
        for (int col = 0; col < E_OUT; ++col)
            wf[(((st * 4 + grp) * 16) + col) * 8 + j] = f2bfs(W[kk * E_OUT + col]);
    }
}

// finer-grained: 2-wave blocks, 16 cells x both batches per block, 4096 blocks.
__global__ __launch_bounds__(THREADS, 3) void mge_kernel(
    const unsigned char* __restrict__ xq,
    const float* __restrict__ meta,
    const float* __restrict__ sigma,
    const float* __restrict__ dist_offsets,
    const short* __restrict__ wf,
    const float* __restrict__ b_out,
    const int*   __restrict__ adjc,
    const int*   __restrict__ nh_mask,
    float* __restrict__ out)
{
    __shared__ float nd_flat[NK * 128];        // 8 KB: unscaled nd, swizzled
    __shared__ int   adj_lds[CPB][NH];
    __shared__ float d_lds[CPB][NH];
    __shared__ float m_lds[CPB][NH];
    __shared__ float scl_lds[CPB][NH][2];      // neighbor quant scales (b0,b1)
    __shared__ float tr_lds[NWAVES][16][TRP];  // epilogue transpose

    const int t    = threadIdx.x;
    const int lane = t & 63;
    const int wv   = t >> 6;
    const int base = blockIdx.x * CPB;

    // ---- distances (pure FMA via meta) + both scales, once per (cell,h) ----
    if (t < CPB * NH) {
        const int cl = t / NH;
        const int h  = t % NH;
        const int n  = base + cl;
        const int a  = adjc[n * NH + h];
        const int m  = nh_mask[n * NH + h];
        adj_lds[cl][h] = a;
        const float4 gc = *(const float4*)(meta + (size_t)n * 8);
        const float4 gn = *(const float4*)(meta + (size_t)a * 8);
        const float2 sn = *(const float2*)(meta + (size_t)a * 8 + 4);
        const float cdl = gn.w * gc.w + gn.z * gc.z;   // cos(dlon)
        float cosd = gc.x * gn.x + gc.y * gn.y * cdl;
        cosd = fminf(fmaxf(cosd, -1.0f + 1e-7f), 1.0f - 1e-7f);
        d_lds[cl][h] = acosf(cosd);
        m_lds[cl][h] = (float)m;
        scl_lds[cl][h][0] = sn.x;
        scl_lds[cl][h][1] = sn.y;
    }

    // ---- B fragments from packed global (tiny, L2-hot) ----
    const int col = lane & 15;
    const int grp = lane >> 4;
    bf16x8 bfrag[8];
    #pragma unroll
    for (int st = 0; st < 8; ++st)
        bfrag[st] = ((const bf16x8*)wf)[(st * 4 + grp) * 16 + col];
    const float obias = b_out[col];

    __syncthreads();

    // ---- lane roles: A-row = lane&15 = (cq, v); grp -> (kos_off, e-half) ----
    const int arow = lane & 15;
    const int cq   = arow >> 2;
    const int v    = arow & 3;
    const int e0   = (grp & 1) * 8;
    const int kos_off = grp >> 1;

    u64 xbA[NH], xbB[NH];

    // quad Q in 0..3: cell-quad = Q&1, batch = Q>>1
#define LOADQ(XB, Q)                                                            \
    {                                                                           \
        const int cl_ = (wv << 3) + (((Q) & 1) << 2) + cq;                      \
        const int b_  = (Q) >> 1;                                               \
        _Pragma("unroll")                                                       \
        for (int h = 0; h < NH; ++h) {                                          \
            const int a = adj_lds[cl_][h];                                      \
            XB[h] = *(const u64*)(xq + (size_t)a * 128 + (b_ << 6) + (v << 4) + e0); \
        }                                                                       \
    }

    // prefetch the two b=0 quads — latency hides under the nd phase
    LOADQ(xbA, 0)
    LOADQ(xbB, 1)

    // ---- nd weights: exp/normalize ONCE per (cell,k), stored unscaled ----
    // 16 cells x 16 k = 256 tasks, 2/thread
    #pragma unroll
    for (int it = 0; it < 2; ++it) {
        const int task = it * THREADS + t;
        const int cl = task >> 4;
        const int k  = task & 15;          // k = o*N_SIG + s
        const int o  = k >> 2;
        const int s  = k & 3;
        const float off     = dist_offsets[o];
        const float inv_sig = 1.0f / sigma[s];
        float raw[NH];
        float sum = 0.0f;
        #pragma unroll
        for (int h = 0; h < NH; ++h) {
            const float df = (d_lds[cl][h] - off) * inv_sig;
            const float e  = __expf(-0.5f * df * df) * m_lds[cl][h];
            raw[h] = e;
            sum += e;
        }
        const float inv = 1.0f / (sum + 1e-8f);
        float* dst = nd_flat + NDOFF(k, cl);
        *(f32x4*)dst       = (f32x4){raw[0] * inv, raw[1] * inv, raw[2] * inv, raw[3] * inv};
        *(f32x4*)(dst + 4) = (f32x4){raw[4] * inv, raw[5] * inv, raw[6] * inv, 0.0f};
    }
    __syncthreads();

#define COMPQ(XB, Q)                                                            \
    {                                                                           \
        const int cl_ = (wv << 3) + (((Q) & 1) << 2) + cq;                      \
        const int b_  = (Q) >> 1;                                               \
        /* dequant per quad: xf = u*sc - 128*sc (f32x2 pk fma) */               \
        f32x2 xf2[NH][4];                                                       \
        _Pragma("unroll")                                                       \
        for (int h = 0; h < NH; ++h) {                                          \
            const float sc = scl_lds[cl_][h][b_];                               \
            const float nb = -128.0f * sc;                                      \
            const f32x2 sc2 = {sc, sc};                                         \
            const f32x2 nb2 = {nb, nb};                                         \
            const unsigned lo = (unsigned)XB[h], hi = (unsigned)(XB[h] >> 32);  \
            f32x2 u;                                                            \
            u = (f32x2){(float)(lo & 0xffu), (float)((lo >> 8) & 0xffu)};       \
            xf2[h][0] = __builtin_elementwise_fma(u, sc2, nb2);                 \
            u = (f32x2){(float)((lo >> 16) & 0xffu), (float)(lo >> 24)};        \
            xf2[h][1] = __builtin_elementwise_fma(u, sc2, nb2);                 \
            u = (f32x2){(float)(hi & 0xffu), (float)((hi >> 8) & 0xffu)};       \
            xf2[h][2] = __builtin_elementwise_fma(u, sc2, nb2);                 \
            u = (f32x2){(float)((hi >> 16) & 0xffu), (float)(hi >> 24)};        \
            xf2[h][3] = __builtin_elementwise_fma(u, sc2, nb2);                 \
        }                                                                       \
        f32x4 acc = {0.f, 0.f, 0.f, 0.f};                                       \
        _Pragma("unroll")                                                       \
        for (int st = 0; st < 8; ++st) {                                        \
            const int k2 = st * 2 + kos_off;                                    \
            const float* ndp = nd_flat + NDOFF(k2, cl_);                        \
            const f32x4 n0 = *(const f32x4*)ndp;                                \
            const f32x4 n1 = *(const f32x4*)(ndp + 4);                          \
            const float nds[NH] = {n0.x, n0.y, n0.z, n0.w, n1.x, n1.y, n1.z};   \
            f32x2 s0 = {0.f, 0.f}, s1 = {0.f, 0.f};                             \
            f32x2 s2 = {0.f, 0.f}, s3 = {0.f, 0.f};                             \
            _Pragma("unroll")                                                   \
            for (int h = 0; h < NH; ++h) {                                      \
                const f32x2 nd2 = {nds[h], nds[h]};                             \
                s0 = __builtin_elementwise_fma(nd2, xf2[h][0], s0);             \
                s1 = __builtin_elementwise_fma(nd2, xf2[h][1], s1);             \
                s2 = __builtin_elementwise_fma(nd2, xf2[h][2], s2);             \
                s3 = __builtin_elementwise_fma(nd2, xf2[h][3], s3);             \
            }                                                                   \
            bf16x8 aa;                                                          \
            aa[0] = f2bfs(s0.x); aa[1] = f2bfs(s0.y);                           \
            aa[2] = f2bfs(s1.x); aa[3] = f2bfs(s1.y);                           \
            aa[4] = f2bfs(s2.x); aa[5] = f2bfs(s2.y);                           \
            aa[6] = f2bfs(s3.x); aa[7] = f2bfs(s3.y);                           \
            acc = __builtin_amdgcn_mfma_f32_16x16x32_bf16(aa, bfrag[st], acc, 0, 0, 0); \
        }                                                                       \
        /* transpose via per-wave LDS tile (wave-private: lgkm-only wait) */    \
        _Pragma("unroll")                                                       \
        for (int r = 0; r < 4; ++r)                                             \
            tr_lds[wv][grp * 4 + r][col] = acc[r] + obias;                      \
        __builtin_amdgcn_s_waitcnt(WAIT_LGKM0);                                 \
        __builtin_amdgcn_sched_barrier(0);                                      \
        {                                                                       \
            const int rr = lane >> 2;                                           \
            const int cc = (lane & 3) << 2;                                     \
            const f32x4 val = *(const f32x4*)&tr_lds[wv][rr][cc];               \
            const size_t qbase = ((size_t)b_ << 16) + base + (wv << 3) + (((Q) & 1) << 2); \
            __builtin_nontemporal_store(val, (f32x4*)(out + qbase * 64 + rr * 16 + cc)); \
        }                                                                       \
    }

    COMPQ(xbA, 0)
    LOADQ(xbA, 2)
    COMPQ(xbB, 1)
    LOADQ(xbB, 3)
    COMPQ(xbA, 2)
    COMPQ(xbB, 3)

#undef LOADQ
#undef COMPQ
}

extern "C" void kernel_launch(void* const* d_in, const int* in_sizes, int n_in,
                              void* d_out, int out_size, void* d_ws, size_t ws_size,
                              hipStream_t stream) {
    const float* x            = (const float*)d_in[0];
    const float* coords       = (const float*)d_in[1];
    const float* sigma        = (const float*)d_in[2];
    const float* dist_offsets = (const float*)d_in[3];
    const float* W            = (const float*)d_in[4];
    const float* b_out        = (const float*)d_in[5];
    const int*   adjc         = (const int*)d_in[6];
    const int*   nh_mask      = (const int*)d_in[7];
    float* out = (float*)d_out;

    char* ws = (char*)d_ws;
    short*         wf   = (short*)ws;                             // 8 KB
    float*         meta = (float*)(ws + 8192);                    // 2 MB
    unsigned char* xq   = (unsigned char*)(ws + 8192 + 2097152);  // 8.4 MB

    setup_kernel<<<2048, 256, 0, stream>>>(x, coords, W, wf, xq, meta);
    dim3 grid(N_CELLS / CPB);
    mge_kernel<<<grid, THREADS, 0, stream>>>(xq, meta, sigma, dist_offsets,
                                             wf, b_out, adjc, nh_mask, out);
}

// Round 21
// 48.007 us; speedup vs baseline: 1.0485x; 1.0485x over previous
//
#include <hip/hip_runtime.h>
#include <hip/hip_bf16.h>
#include <math.h>

#define N_CELLS 65536
#define NH 7
#define NV 4
#define E_IN 16
#define E_OUT 16
#define NK 16            // N_OFF * N_SIG

#define CPB 32           // cells per block (4 waves x 2 cell-quads x 4 cells)
#define THREADS 256
#define TRP 20           // transpose row pad

typedef __attribute__((ext_vector_type(8))) short bf16x8;
typedef __attribute__((ext_vector_type(4))) float f32x4;
typedef __attribute__((ext_vector_type(2))) float f32x2;
typedef unsigned long long u64;

// swizzled nd index: row (k, cl) at word (k<<8) + ((cl ^ (k&3))<<3)
#define NDOFF(k, cl) (((k) << 8) + ((((cl) ^ ((k) & 3))) << 3))

static __device__ __forceinline__ short f2bfs(float f) {
    __hip_bfloat16 h = __float2bfloat16(f);
    short s;
    __builtin_memcpy(&s, &h, 2);
    return s;
}

// ---------------- setup ----------------
// xq[cell][b][v][e] u8 : one cell = one 128B line (both batches)
// meta[cell][8] f32    : {sinlat, coslat, sinlon, coslon, s_b0, s_b1, 0, 0}
// wf : per-lane MFMA B-fragment layout [st][grp][col][j] bf16 (8 KB)
__global__ __launch_bounds__(256) void setup_kernel(
    const float* __restrict__ x, const float* __restrict__ coords,
    const float* __restrict__ W,
    short* __restrict__ wf, unsigned char* __restrict__ xq, float* __restrict__ meta)
{
    const int t = threadIdx.x;
    const int g = blockIdx.x * 64 + (t >> 2);   // group = b*N_CELLS + cell
    const int p = t & 3;

    const float4* src = (const float4*)(x + (size_t)g * 64 + p * 16);
    float4 q[4];
    #pragma unroll
    for (int i = 0; i < 4; ++i) q[i] = src[i];

    float amax = 0.0f;
    #pragma unroll
    for (int i = 0; i < 4; ++i)
        amax = fmaxf(amax, fmaxf(fmaxf(fabsf(q[i].x), fabsf(q[i].y)),
                                 fmaxf(fabsf(q[i].z), fabsf(q[i].w))));
    amax = fmaxf(amax, __shfl_xor(amax, 1));
    amax = fmaxf(amax, __shfl_xor(amax, 2));
    amax = fmaxf(amax, 1e-12f);

    const float inv = 127.0f / amax;
    const float s   = amax / 127.0f;

    unsigned int w[4];
    #pragma unroll
    for (int i = 0; i < 4; ++i) {
        const float vs[4] = {q[i].x, q[i].y, q[i].z, q[i].w};
        unsigned int ww = 0;
        #pragma unroll
        for (int j = 0; j < 4; ++j) {
            float r = rintf(vs[j] * inv);
            r = fminf(fmaxf(r, -127.0f), 127.0f);
            ww |= ((unsigned int)(int)(r + 128.0f) & 0xffu) << (8 * j);
        }
        w[i] = ww;
    }
    const int cell = g & (N_CELLS - 1);
    const int b    = g >> 16;
    *(uint4*)(xq + (size_t)cell * 128 + b * 64 + p * 16) = make_uint4(w[0], w[1], w[2], w[3]);

    if (p == 0) meta[(size_t)cell * 8 + 4 + b] = s;

    if (p == 0 && b == 0) {            // one thread per cell: geometry
        const float lat = coords[cell];
        const float lon = coords[N_CELLS + cell];
        meta[(size_t)cell * 8 + 0] = sinf(lat);
        meta[(size_t)cell * 8 + 1] = cosf(lat);
        meta[(size_t)cell * 8 + 2] = sinf(lon);
        meta[(size_t)cell * 8 + 3] = cosf(lon);
        meta[(size_t)cell * 8 + 6] = 0.0f;
        meta[(size_t)cell * 8 + 7] = 0.0f;
    }

    if (blockIdx.x == 0) {
        const int kk  = t;                 // flat K = k_os*16 + e, 0..255
        const int j   = kk & 7;
        const int grp = (kk >> 3) & 3;
        const int st  = kk >> 5;
        #pragma unroll
        for (int col = 0; col < E_OUT; ++col)
            wf[(((st * 4 + grp) * 16) + col) * 8 + j] = f2bfs(W[kk * E_OUT + col]);
    }
}

// single dispatch: each block does 32 cells x BOTH batches.
// nd/exp phase computed once per cell (b-independent), scale-folded per b.
__global__ __launch_bounds__(THREADS, 3) void mge_kernel(
    const unsigned char* __restrict__ xq,
    const float* __restrict__ meta,
    const float* __restrict__ sigma,
    const float* __restrict__ dist_offsets,
    const short* __restrict__ wf,
    const float* __restrict__ b_out,
    const int*   __restrict__ adjc,
    const int*   __restrict__ nh_mask,
    float* __restrict__ out)
{
    __shared__ float nd_flat[2][NK * 256];     // 32 KB: scale-folded nd per batch
    __shared__ int   adj_lds[CPB][NH];
    __shared__ float d_lds[CPB][NH];
    __shared__ float m_lds[CPB][NH];
    __shared__ float scl_lds[CPB][NH][2];      // neighbor quant scales (b0,b1)
    __shared__ float tr_lds[4][16][TRP];       // epilogue transpose, 5.1 KB

    const int t    = threadIdx.x;
    const int lane = t & 63;
    const int wv   = t >> 6;
    const int base = blockIdx.x * CPB;

    // ---- distances (pure FMA via meta) + both scales, once per (cell,h) ----
    if (t < CPB * NH) {
        const int cl = t / NH;
        const int h  = t % NH;
        const int n  = base + cl;
        const int a  = adjc[n * NH + h];
        const int m  = nh_mask[n * NH + h];
        adj_lds[cl][h] = a;
        const float4 gc = *(const float4*)(meta + (size_t)n * 8);
        const float4 gn = *(const float4*)(meta + (size_t)a * 8);
        const float2 sn = *(const float2*)(meta + (size_t)a * 8 + 4);
        const float cdl = gn.w * gc.w + gn.z * gc.z;   // cos(dlon)
        float cosd = gc.x * gn.x + gc.y * gn.y * cdl;
        cosd = fminf(fmaxf(cosd, -1.0f + 1e-7f), 1.0f - 1e-7f);
        d_lds[cl][h] = acosf(cosd);
        m_lds[cl][h] = (float)m;
        scl_lds[cl][h][0] = sn.x;
        scl_lds[cl][h][1] = sn.y;
    }

    // ---- B fragments from packed global (tiny, L2-hot) ----
    const int col = lane & 15;
    const int grp = lane >> 4;
    bf16x8 bfrag[8];
    #pragma unroll
    for (int st = 0; st < 8; ++st)
        bfrag[st] = ((const bf16x8*)wf)[(st * 4 + grp) * 16 + col];
    const float obias = b_out[col];

    __syncthreads();

    // ---- lane roles: A-row = lane&15 = (cq, v); grp -> (kos_off, e-half) ----
    const int arow = lane & 15;
    const int cq   = arow >> 2;
    const int v    = arow & 3;
    const int e0   = (grp & 1) * 8;
    const int kos_off = grp >> 1;

    u64 xbA[NH], xbB[NH];

    // quad Q in 0..3: cell-quad = Q&1, batch = Q>>1
#define LOADQ(XB, Q)                                                            \
    {                                                                           \
        const int cl_ = (wv << 3) + (((Q) & 1) << 2) + cq;                      \
        const int b_  = (Q) >> 1;                                               \
        _Pragma("unroll")                                                       \
        for (int h = 0; h < NH; ++h) {                                          \
            const int a = adj_lds[cl_][h];                                      \
            XB[h] = *(const u64*)(xq + (size_t)a * 128 + (b_ << 6) + (v << 4) + e0); \
        }                                                                       \
    }

    // prefetch the two b=0 quads — latency hides under the nd phase
    LOADQ(xbA, 0)
    LOADQ(xbB, 1)

    // ---- nd weights: exp/normalize ONCE per (cell,k); fold scales per b ----
    // nd_b[h] = nd[h]*sc_b[h]; slot7 = -128 * sum_h nd_b[h]
    #pragma unroll
    for (int it = 0; it < 2; ++it) {
        const int task = it * THREADS + t;
        const int cl = task >> 4;
        const int k  = task & 15;          // k = o*N_SIG + s
        const int o  = k >> 2;
        const int s  = k & 3;
        const float off     = dist_offsets[o];
        const float inv_sig = 1.0f / sigma[s];
        float raw[NH];
        float sum = 0.0f;
        #pragma unroll
        for (int h = 0; h < NH; ++h) {
            const float df = (d_lds[cl][h] - off) * inv_sig;
            const float e  = __expf(-0.5f * df * df) * m_lds[cl][h];
            raw[h] = e;
            sum += e;
        }
        const float inv = 1.0f / (sum + 1e-8f);
        float nd0[NH], nd1[NH];
        float cb0 = 0.0f, cb1 = 0.0f;
        #pragma unroll
        for (int h = 0; h < NH; ++h) {
            const float nd = raw[h] * inv;
            nd0[h] = nd * scl_lds[cl][h][0];
            nd1[h] = nd * scl_lds[cl][h][1];
            cb0 += nd0[h];
            cb1 += nd1[h];
        }
        float* dst0 = &nd_flat[0][NDOFF(k, cl)];
        *(f32x4*)dst0       = (f32x4){nd0[0], nd0[1], nd0[2], nd0[3]};
        *(f32x4*)(dst0 + 4) = (f32x4){nd0[4], nd0[5], nd0[6], -128.0f * cb0};
        float* dst1 = &nd_flat[1][NDOFF(k, cl)];
        *(f32x4*)dst1       = (f32x4){nd1[0], nd1[1], nd1[2], nd1[3]};
        *(f32x4*)(dst1 + 4) = (f32x4){nd1[4], nd1[5], nd1[6], -128.0f * cb1};
    }
    __syncthreads();

#define COMPQ(XB, Q)                                                            \
    {                                                                           \
        const int cl_ = (wv << 3) + (((Q) & 1) << 2) + cq;                      \
        const int b_  = (Q) >> 1;                                               \
        /* byte -> f32 pairs (v_cvt_f32_ubyte); dequant folded into nd */       \
        f32x2 u2[NH][4];                                                        \
        _Pragma("unroll")                                                       \
        for (int h = 0; h < NH; ++h) {                                          \
            const unsigned lo = (unsigned)XB[h], hi = (unsigned)(XB[h] >> 32);  \
            u2[h][0] = (f32x2){(float)(lo & 0xffu), (float)((lo >> 8) & 0xffu)};  \
            u2[h][1] = (f32x2){(float)((lo >> 16) & 0xffu), (float)(lo >> 24)};   \
            u2[h][2] = (f32x2){(float)(hi & 0xffu), (float)((hi >> 8) & 0xffu)};  \
            u2[h][3] = (f32x2){(float)((hi >> 16) & 0xffu), (float)(hi >> 24)};   \
        }                                                                       \
        const float* ndbase = nd_flat[b_];                                      \
        f32x4 acc = {0.f, 0.f, 0.f, 0.f};                                       \
        _Pragma("unroll")                                                       \
        for (int st = 0; st < 8; ++st) {                                        \
            const int k2 = st * 2 + kos_off;                                    \
            const float* ndp = ndbase + NDOFF(k2, cl_);                         \
            const f32x4 n0 = *(const f32x4*)ndp;                                \
            const f32x4 n1 = *(const f32x4*)(ndp + 4);                          \
            const float nds[NH] = {n0.x, n0.y, n0.z, n0.w, n1.x, n1.y, n1.z};   \
            const float ng = n1.w;                                              \
            f32x2 s0 = {ng, ng}, s1 = {ng, ng};                                 \
            f32x2 s2 = {ng, ng}, s3 = {ng, ng};                                 \
            _Pragma("unroll")                                                   \
            for (int h = 0; h < NH; ++h) {                                      \
                const f32x2 nd2 = {nds[h], nds[h]};                             \
                s0 = s0 + nd2 * u2[h][0];                                       \
                s1 = s1 + nd2 * u2[h][1];                                       \
                s2 = s2 + nd2 * u2[h][2];                                       \
                s3 = s3 + nd2 * u2[h][3];                                       \
            }                                                                   \
            bf16x8 aa;                                                          \
            aa[0] = f2bfs(s0.x); aa[1] = f2bfs(s0.y);                           \
            aa[2] = f2bfs(s1.x); aa[3] = f2bfs(s1.y);                           \
            aa[4] = f2bfs(s2.x); aa[5] = f2bfs(s2.y);                           \
            aa[6] = f2bfs(s3.x); aa[7] = f2bfs(s3.y);                           \
            acc = __builtin_amdgcn_mfma_f32_16x16x32_bf16(aa, bfrag[st], acc, 0, 0, 0); \
        }                                                                       \
        /* transpose via per-wave LDS tile, then full-line nt store */          \
        _Pragma("unroll")                                                       \
        for (int r = 0; r < 4; ++r)                                             \
            tr_lds[wv][grp * 4 + r][col] = acc[r] + obias;                      \
        __builtin_amdgcn_s_waitcnt(0);                                          \
        {                                                                       \
            const int rr = lane >> 2;                                           \
            const int cc = (lane & 3) << 2;                                     \
            const f32x4 val = *(const f32x4*)&tr_lds[wv][rr][cc];               \
            const size_t qbase = ((size_t)b_ << 16) + base + (wv << 3) + (((Q) & 1) << 2); \
            __builtin_nontemporal_store(val, (f32x4*)(out + qbase * 64 + rr * 16 + cc)); \
        }                                                                       \
    }

    COMPQ(xbA, 0)
    LOADQ(xbA, 2)
    COMPQ(xbB, 1)
    LOADQ(xbB, 3)
    COMPQ(xbA, 2)
    COMPQ(xbB, 3)

#undef LOADQ
#undef COMPQ
}

extern "C" void kernel_launch(void* const* d_in, const int* in_sizes, int n_in,
                              void* d_out, int out_size, void* d_ws, size_t ws_size,
                              hipStream_t stream) {
    const float* x            = (const float*)d_in[0];
    const float* coords       = (const float*)d_in[1];
    const float* sigma        = (const float*)d_in[2];
    const float* dist_offsets = (const float*)d_in[3];
    const float* W            = (const float*)d_in[4];
    const float* b_out        = (const float*)d_in[5];
    const int*   adjc         = (const int*)d_in[6];
    const int*   nh_mask      = (const int*)d_in[7];
    float* out = (float*)d_out;

    char* ws = (char*)d_ws;
    short*         wf   = (short*)ws;                             // 8 KB
    float*         meta = (float*)(ws + 8192);                    // 2 MB
    unsigned char* xq   = (unsigned char*)(ws + 8192 + 2097152);  // 8.4 MB

    setup_kernel<<<2048, 256, 0, stream>>>(x, coords, W, wf, xq, meta);
    dim3 grid(N_CELLS / CPB);
    mge_kernel<<<grid, THREADS, 0, stream>>>(xq, meta, sigma, dist_offsets,
                                             wf, b_out, adjc, nh_mask, out);
}